// Round 4
// baseline (674.765 us; speedup 1.0000x reference)
//
#include <hip/hip_runtime.h>

#define BB 32
#define CKD 64
#define CC 8
#define KK 8
#define TT 64

// level tables (compile-time; N=8192, 13 levels)
__device__ const int D_CB[14] = {0,16,32,48,56,60,62,63,64,65,66,67,68,69};   // fwd chunk prefix
__device__ const int D_TILES[13] = {64,32,16,8,4,2,1,1,1,1,1,1,1};
__device__ const int D_GB[14] = {0,8,12,14,15,16,17,18,19,20,21,22,23,24};    // inv 8-tile group prefix
__device__ const int D_LS[14] = {0,64,128,192,256,320,384,417,434,443,448,451,453,454}; // mix l prefix
__device__ const int D_L[13]  = {64,64,64,64,64,64,33,17,9,5,3,2,1};

static __device__ __forceinline__ float4 ld4(const float* p){ return *(const float4*)p; }
static __device__ __forceinline__ size_t d_udo(int i){ return 33554432ull - (16777216u >> i); }
static __device__ __forceinline__ size_t d_uso(int i){ return 50329600ull - (16777216u >> i); }

// ---------------- decompose: x[b,2t,c,:],x[b,2t+1,c,:] -> d,s via ec_d/ec_s (16x8)
__global__ __launch_bounds__(256) void decomp_k(const float* __restrict__ xin,
        const float* __restrict__ ecd, const float* __restrict__ ecs,
        float* __restrict__ dslot, float* __restrict__ sslot, int nh) {
    int idx = blockIdx.x * 256 + threadIdx.x;
    if (idx >= BB * nh * CC) return;
    int c = idx & 7;
    int t = (idx >> 3) % nh;
    int b = idx / (nh * CC);
    const float* p0 = xin + ((size_t)b * 2 * nh + 2 * t) * CKD + c * KK;
    float xa[16];
    float4 v;
    v = ld4(p0);      xa[0]=v.x; xa[1]=v.y; xa[2]=v.z; xa[3]=v.w;
    v = ld4(p0+4);    xa[4]=v.x; xa[5]=v.y; xa[6]=v.z; xa[7]=v.w;
    v = ld4(p0+64);   xa[8]=v.x; xa[9]=v.y; xa[10]=v.z; xa[11]=v.w;
    v = ld4(p0+68);   xa[12]=v.x; xa[13]=v.y; xa[14]=v.z; xa[15]=v.w;
    float dd[8], ss[8];
    #pragma unroll
    for (int m = 0; m < 8; m++) { dd[m] = 0.f; ss[m] = 0.f; }
    #pragma unroll
    for (int j = 0; j < 16; j++) {
        float xv = xa[j];
        #pragma unroll
        for (int m = 0; m < 8; m++) {
            dd[m] = fmaf(xv, ecd[j*8+m], dd[m]);
            ss[m] = fmaf(xv, ecs[j*8+m], ss[m]);
        }
    }
    size_t ob = ((size_t)b * nh + t) * CKD + c * KK;
    *(float4*)(dslot+ob)   = make_float4(dd[0],dd[1],dd[2],dd[3]);
    *(float4*)(dslot+ob+4) = make_float4(dd[4],dd[5],dd[6],dd[7]);
    *(float4*)(sslot+ob)   = make_float4(ss[0],ss[1],ss[2],ss[3]);
    *(float4*)(sslot+ob+4) = make_float4(ss[4],ss[5],ss[6],ss[7]);
}

// ---------------- forward truncated DFT, ALL levels, computed twiddles (no tables).
// grid (69 chunk-slots, 32 b, 2 ds). Partial per slot, no atomics.
__global__ __launch_bounds__(256) void fft_fwd_all_k(const float* __restrict__ outbuf,
        float2* __restrict__ xfp) {
    __shared__ float4 vt4[TT*CKD/4];   // 16 KB  value tile [t][i]
    float* vt = (float*)vt4;
    int slot = blockIdx.x;
    int lvl = 0;
    while (lvl < 12 && slot >= D_CB[lvl+1]) lvl++;
    int nh = 4096 >> lvl;
    int tiles = D_TILES[lvl];
    int ch = D_CB[lvl+1] - D_CB[lvl];
    int tpc = tiles / ch;
    int b = blockIdx.y;
    const float* V = outbuf + (blockIdx.z ? d_uso(lvl) : d_udo(lvl)) + (size_t)b * nh * CKD;
    int tid = threadIdx.x;
    int tx = tid & 15, ty = tid >> 4;
    int tile0 = (slot - D_CB[lvl]) * tpc;
    int tile1 = tile0 + tpc;
    float rn = 6.283185307179586f / (float)nh;
    float2 acc[4][4];
    #pragma unroll
    for (int a = 0; a < 4; a++)
        #pragma unroll
        for (int i = 0; i < 4; i++) acc[a][i] = make_float2(0.f, 0.f);
    for (int tile = tile0; tile < tile1; tile++) {
        int tbase = tile * TT;
        __syncthreads();
        #pragma unroll
        for (int q = 0; q < 4; q++) {
            int fi = tid + 256*q;
            int r = fi >> 4;
            float4 v = make_float4(0.f,0.f,0.f,0.f);
            if (tbase + r < nh) v = ld4(V + (size_t)(tbase + r)*CKD + (fi & 15)*4);
            vt4[fi] = v;
        }
        __syncthreads();
        // twiddle chains: cs_a(t) = cis(2*pi*x_a*t/nh), x_a = ty*4+a
        float2 cs[4], om[4];
        #pragma unroll
        for (int a = 0; a < 4; a++) {
            int xm = ty*4 + a;
            int r0 = (xm * tbase) & (nh - 1);
            __sincosf(rn * (float)r0, &cs[a].y, &cs[a].x);
            int r1 = xm & (nh - 1);
            __sincosf(rn * (float)r1, &om[a].y, &om[a].x);
        }
        #pragma unroll 4
        for (int t = 0; t < TT; t++) {
            float4 vv  = *(float4*)&vt[t*CKD + tx*4];
            float vr[4] = {vv.x, vv.y, vv.z, vv.w};
            #pragma unroll
            for (int a = 0; a < 4; a++) {
                #pragma unroll
                for (int i = 0; i < 4; i++) {
                    acc[a][i].x = fmaf(cs[a].x,  vr[i], acc[a][i].x);
                    acc[a][i].y = fmaf(-cs[a].y, vr[i], acc[a][i].y);
                }
                float nre = cs[a].x*om[a].x - cs[a].y*om[a].y;
                cs[a].y   = cs[a].x*om[a].y + cs[a].y*om[a].x;
                cs[a].x   = nre;
            }
        }
    }
    int x0 = ty*4, i0 = tx*4;
    float2* XFP = xfp + (((size_t)slot*BB + b)*2 + blockIdx.z)*4096;
    #pragma unroll
    for (int a = 0; a < 4; a++)
        #pragma unroll
        for (int i = 0; i < 4; i++)
            XFP[(x0+a)*64 + i0 + i] = acc[a][i];
}

// ---------------- sum per-chunk partials into xf_all[level]
__global__ __launch_bounds__(256) void reduce_all_k(const float2* __restrict__ xfp,
        float2* __restrict__ xf_all) {
    int lvl = blockIdx.y;
    int e = blockIdx.x * 256 + threadIdx.x;      // e < BB*2*4096
    int j = e & 4095;
    int z = (e >> 12) & 1;
    int b = e >> 13;
    int c0 = D_CB[lvl], c1 = D_CB[lvl+1];
    size_t stride = (size_t)BB*2*4096;
    size_t base = (((size_t)c0*BB + b)*2 + z)*4096 + j;
    float2 a = xfp[base];
    for (int c = c0+1; c < c1; c++) {
        base += stride;
        float2 p = xfp[base];
        a.x += p.x; a.y += p.y;
    }
    xf_all[(size_t)lvl*262144 + ((size_t)b*2 + z)*4096 + j] = a;
}

// ---------------- spectral mix, ALL levels: block = (level, mode x)
__global__ __launch_bounds__(256) void mix_all_k(const float2* __restrict__ xf_all,
        const float* __restrict__ wAr, const float* __restrict__ wAi,
        const float* __restrict__ wBr, const float* __restrict__ wBi,
        const float* __restrict__ wCr, const float* __restrict__ wCi,
        float2* __restrict__ of_all) {
    int lvl = 0;
    while (lvl < 12 && (int)blockIdx.x >= D_LS[lvl+1]) lvl++;
    int x = blockIdx.x - D_LS[lvl];
    int nh = 4096 >> lvl;
    const float2* xfL = xf_all + (size_t)lvl*262144;
    float2* ofL = of_all + (size_t)lvl*262144;
    int tid = threadIdx.x;
    int o = tid & 63, wq = tid >> 6;
    __shared__ float2 sxd[BB*CKD];     // 16 KB
    __shared__ float2 sxs[BB*CKD];     // 16 KB
    __shared__ float  swt[6][16*CKD];  // 24 KB
    for (int q = tid; q < BB*CKD; q += 256) {
        int b = q >> 6, i = q & 63;
        sxd[q] = xfL[((size_t)b*2 + 0)*4096 + x*64 + i];
        sxs[q] = xfL[((size_t)b*2 + 1)*4096 + x*64 + i];
    }
    float2 aud[8], aus[8];
    #pragma unroll
    for (int j=0;j<8;j++){ aud[j]=make_float2(0.f,0.f); aus[j]=make_float2(0.f,0.f); }
    for (int ic = 0; ic < 4; ic++) {
        __syncthreads();
        for (int q = tid; q < 16*CKD; q += 256) {
            int ii = q >> 6, oo = q & 63;
            size_t a = ((size_t)(ic*16+ii)*64 + oo)*64 + x;
            swt[0][q] = wAr[a]; swt[1][q] = wAi[a];
            swt[2][q] = wBr[a]; swt[3][q] = wBi[a];
            swt[4][q] = wCr[a]; swt[5][q] = wCi[a];
        }
        __syncthreads();
        #pragma unroll 4
        for (int ii = 0; ii < 16; ii++) {
            float ar = swt[0][ii*64+o], ai_ = swt[1][ii*64+o];
            float br = swt[2][ii*64+o], bi_ = swt[3][ii*64+o];
            float cr = swt[4][ii*64+o], ci_ = swt[5][ii*64+o];
            int i = ic*16 + ii;
            #pragma unroll
            for (int j = 0; j < 8; j++) {
                float2 xd = sxd[(wq*8+j)*64 + i];
                float2 xs = sxs[(wq*8+j)*64 + i];
                aud[j].x += xd.x*ar - xd.y*ai_ + xs.x*br - xs.y*bi_;
                aud[j].y += xd.x*ai_ + xd.y*ar + xs.x*bi_ + xs.y*br;
                aus[j].x += xd.x*cr - xd.y*ci_;
                aus[j].y += xd.x*ci_ + xd.y*cr;
            }
        }
    }
    float w = (x == 0 || 2*x == nh) ? 1.f : 2.f;   // irfft doubling; DC/Nyquist not doubled
    float sc = w / (float)nh;
    #pragma unroll
    for (int j = 0; j < 8; j++) {
        int b = wq*8 + j;
        ofL[((size_t)b*2 + 0)*4096 + x*64 + o] = make_float2(sc*aud[j].x, -sc*aud[j].y);
        ofL[((size_t)b*2 + 1)*4096 + x*64 + o] = make_float2(sc*aus[j].x, -sc*aus[j].y);
    }
}

// ---------------- inverse truncated DFT, ALL levels: 8 tiles per block,
// sof split into two [64][16]-float4 arrays (2-way banks = free), computed twiddles.
__global__ __launch_bounds__(256) void fft_inv_all_k(const float2* __restrict__ of_all,
        float* __restrict__ outbuf) {
    __shared__ float4 sofA[64*16];  // 16 KB  o-pairs (4tx, 4tx+1)
    __shared__ float4 sofB[64*16];  // 16 KB  o-pairs (4tx+2, 4tx+3)
    int lvl = 0;
    while (lvl < 12 && (int)blockIdx.x >= D_GB[lvl+1]) lvl++;
    int g = blockIdx.x - D_GB[lvl];
    int nh = 4096 >> lvl;
    int l = D_L[lvl];
    int b = blockIdx.y, z = blockIdx.z;
    const float4* OF4 = (const float4*)(of_all + (size_t)lvl*262144 + ((size_t)b*2 + z)*4096);
    float* U = outbuf + (z ? d_uso(lvl) : d_udo(lvl)) + (size_t)b * nh * CKD;
    int tid = threadIdx.x;
    int tx = tid & 15, ty = tid >> 4;
    float rn = 6.283185307179586f / (float)nh;
    #pragma unroll
    for (int q = 0; q < 8; q++) {
        int fi = tid + 256*q;                 // fi = x*32 + oq
        int x = fi >> 5, oq = fi & 31;
        float4 v = make_float4(0.f,0.f,0.f,0.f);
        if (x < l) v = OF4[fi];
        ((oq & 1) ? sofB : sofA)[x*16 + (oq >> 1)] = v;
    }
    __syncthreads();
    for (int ti = 0; ti < 8; ti++) {
        int tbase = (g*8 + ti) * TT;
        if (tbase >= nh) break;
        int t0 = tbase + ty*4;
        float u[4][4];
        float2 cs[4], om[4];
        #pragma unroll
        for (int tj = 0; tj < 4; tj++) {
            #pragma unroll
            for (int j = 0; j < 4; j++) u[tj][j] = 0.f;
            cs[tj] = make_float2(1.f, 0.f);
            int r1 = (t0 + tj) & (nh - 1);
            __sincosf(rn * (float)r1, &om[tj].y, &om[tj].x);
        }
        #pragma unroll 4
        for (int x = 0; x < 64; x++) {
            float4 p0 = sofA[x*16 + tx];
            float4 p1 = sofB[x*16 + tx];
            #pragma unroll
            for (int tj = 0; tj < 4; tj++) {
                u[tj][0] = fmaf(cs[tj].x, p0.x, fmaf(cs[tj].y, p0.y, u[tj][0]));
                u[tj][1] = fmaf(cs[tj].x, p0.z, fmaf(cs[tj].y, p0.w, u[tj][1]));
                u[tj][2] = fmaf(cs[tj].x, p1.x, fmaf(cs[tj].y, p1.y, u[tj][2]));
                u[tj][3] = fmaf(cs[tj].x, p1.z, fmaf(cs[tj].y, p1.w, u[tj][3]));
                float nre = cs[tj].x*om[tj].x - cs[tj].y*om[tj].y;
                cs[tj].y  = cs[tj].x*om[tj].y + cs[tj].y*om[tj].x;
                cs[tj].x  = nre;
            }
        }
        #pragma unroll
        for (int tj = 0; tj < 4; tj++) {
            int t = t0 + tj;
            if (t < nh)
                *(float4*)(U + (size_t)t*CKD + tx*4) = make_float4(u[tj][0],u[tj][1],u[tj][2],u[tj][3]);
        }
    }
}

// ---------------- coarsest-level linear: x @ T0_w.T + b
__global__ __launch_bounds__(256) void t0_k(const float* __restrict__ xin,
        const float* __restrict__ w, const float* __restrict__ bias,
        float* __restrict__ xout) {
    int idx = blockIdx.x*256 + threadIdx.x;
    if (idx >= BB*CKD) return;
    int m = idx & 7, c = (idx >> 3) & 7, b = idx >> 6;
    const float* xr = xin + (size_t)b*CKD + c*KK;
    float acc = bias[m];
    #pragma unroll
    for (int j = 0; j < 8; j++) acc = fmaf(xr[j], w[m*8+j], acc);
    xout[idx] = acc;
}

// ---------------- reconstruct one level: (x+Us, Ud) @ rc_e / rc_o, interleave even/odd
__global__ __launch_bounds__(256) void recon_k(const float* __restrict__ xin,
        const float* __restrict__ us, const float* __restrict__ ud,
        const float* __restrict__ rce, const float* __restrict__ rco,
        float* __restrict__ xout, int nh) {
    int idx = blockIdx.x*256 + threadIdx.x;
    if (idx >= BB*nh*CC) return;
    int c = idx & 7;
    int t = (idx >> 3) % nh;
    int b = idx / (nh*CC);
    size_t base = ((size_t)b*nh + t)*CKD + c*KK;
    float xc[16];
    float4 a0 = ld4(xin+base), a1 = ld4(xin+base+4);
    float4 u0 = ld4(us+base),  u1 = ld4(us+base+4);
    float4 d0 = ld4(ud+base),  d1 = ld4(ud+base+4);
    xc[0]=a0.x+u0.x; xc[1]=a0.y+u0.y; xc[2]=a0.z+u0.z; xc[3]=a0.w+u0.w;
    xc[4]=a1.x+u1.x; xc[5]=a1.y+u1.y; xc[6]=a1.z+u1.z; xc[7]=a1.w+u1.w;
    xc[8]=d0.x;  xc[9]=d0.y;  xc[10]=d0.z; xc[11]=d0.w;
    xc[12]=d1.x; xc[13]=d1.y; xc[14]=d1.z; xc[15]=d1.w;
    float e[8], o2[8];
    #pragma unroll
    for (int m = 0; m < 8; m++) { e[m] = 0.f; o2[m] = 0.f; }
    #pragma unroll
    for (int j = 0; j < 16; j++) {
        float xv = xc[j];
        #pragma unroll
        for (int m = 0; m < 8; m++) {
            e[m]  = fmaf(xv, rce[j*8+m], e[m]);
            o2[m] = fmaf(xv, rco[j*8+m], o2[m]);
        }
    }
    size_t ob = ((size_t)b*2*nh + 2*t)*CKD + c*KK;
    *(float4*)(xout+ob)      = make_float4(e[0],e[1],e[2],e[3]);
    *(float4*)(xout+ob+4)    = make_float4(e[4],e[5],e[6],e[7]);
    *(float4*)(xout+ob+64)   = make_float4(o2[0],o2[1],o2[2],o2[3]);
    *(float4*)(xout+ob+68)   = make_float4(o2[4],o2[5],o2[6],o2[7]);
}

extern "C" void kernel_launch(void* const* d_in, const int* in_sizes, int n_in,
                              void* d_out, int out_size, void* d_ws, size_t ws_size,
                              hipStream_t stream) {
    const float* x   = (const float*)d_in[0];
    const float* wAr = (const float*)d_in[1];
    const float* wAi = (const float*)d_in[2];
    const float* wBr = (const float*)d_in[3];
    const float* wBi = (const float*)d_in[4];
    const float* wCr = (const float*)d_in[5];
    const float* wCi = (const float*)d_in[6];
    const float* T0w = (const float*)d_in[7];
    const float* T0b = (const float*)d_in[8];
    const float* ecs = (const float*)d_in[9];
    const float* ecd = (const float*)d_in[10];
    const float* rce = (const float*)d_in[11];
    const float* rco = (const float*)d_in[12];
    float* out = (float*)d_out;
    float* wsf = (float*)d_ws;

    // workspace layout (floats)
    size_t p = 0;
    float2* xf_all = (float2*)(wsf + p); p += 13ull*262144*2;   // 26 MB
    float2* of_all = (float2*)(wsf + p); p += 13ull*262144*2;   // 26 MB
    float*  xt0  = wsf + p; p += 2048;
    float*  rb0  = wsf + p; p += 4194304;
    float*  rb1  = wsf + p; p += 8388608;
    float2* xfp  = (float2*)(wsf + p); p += 69ull*BB*2*4096*2;  // 145 MB
    (void)ws_size; (void)in_sizes; (void)n_in; (void)out_size;

    size_t udo[13], uso[13];
    for (int i = 0; i < 13; i++) {
        udo[i] = 33554432ull - (16777216u >> i);
        uso[i] = 50329600ull - (16777216u >> i);
    }

    // sequential decomposition chain (s feeds next level)
    for (int i = 0; i < 13; i++) {
        int nh = 4096 >> i;
        const float* xin_l = (i == 0) ? x : (out + uso[i-1]);
        int tot = BB * nh * CC;
        decomp_k<<<(tot + 255)/256, 256, 0, stream>>>(xin_l, ecd, ecs, out + udo[i], out + uso[i], nh);
    }
    // coarsest-level linear (reads s_12 before inv overwrites it)
    t0_k<<<(BB*CKD + 255)/256, 256, 0, stream>>>(out + uso[12], T0w, T0b, xt0);

    // all-levels spectral pipeline: fwd -> reduce -> mix -> inv
    fft_fwd_all_k<<<dim3(69, BB, 2), 256, 0, stream>>>(out, xfp);
    reduce_all_k<<<dim3(1024, 13), 256, 0, stream>>>(xfp, xf_all);
    mix_all_k<<<454, 256, 0, stream>>>(xf_all, wAr, wAi, wBr, wBi, wCr, wCi, of_all);
    fft_inv_all_k<<<dim3(24, BB, 2), 256, 0, stream>>>(of_all, out);

    // sequential reconstruction chain
    const float* rin = xt0;
    for (int i = 12; i >= 0; i--) {
        int nh = 4096 >> i;
        float* ro = (i == 0) ? out : ((i & 1) ? rb1 : rb0);
        int tot = BB * nh * CC;
        recon_k<<<(tot + 255)/256, 256, 0, stream>>>(rin, out + uso[i], out + udo[i], rce, rco, ro, nh);
        rin = ro;
    }
}

// Round 5
// 589.644 us; speedup vs baseline: 1.1444x; 1.1444x over previous
//
#include <hip/hip_runtime.h>

#define BB 32
#define CKD 64
#define CC 8
#define KK 8
#define TT 64

// level tables (compile-time; N=8192, 13 levels)
__device__ const int D_CB[14] = {0,16,32,48,56,60,62,63,64,65,66,67,68,69};   // fwd chunk prefix
__device__ const int D_TILES[13] = {64,32,16,8,4,2,1,1,1,1,1,1,1};
__device__ const int D_TB[14] = {0,64,96,112,120,124,126,127,128,129,130,131,132,133}; // inv 64-t tile prefix
__device__ const int D_LS[14] = {0,64,128,192,256,320,384,417,434,443,448,451,453,454}; // mix l prefix
__device__ const int D_L[13]  = {64,64,64,64,64,64,33,17,9,5,3,2,1};

typedef __attribute__((ext_vector_type(4))) short s4v;
typedef __attribute__((ext_vector_type(8))) short s8v;
typedef __attribute__((ext_vector_type(4))) float f4v;

static __device__ __forceinline__ float4 ld4(const float* p){ return *(const float4*)p; }
static __device__ __forceinline__ size_t d_udo(int i){ return 33554432ull - (16777216u >> i); }
static __device__ __forceinline__ size_t d_uso(int i){ return 50329600ull - (16777216u >> i); }
static __device__ __forceinline__ size_t d_tof(int i){ return 128ull * (8192u - (8192u >> i)); }

static __device__ __forceinline__ unsigned short b16(float f) {
    unsigned u = __float_as_uint(f);
    u += 0x7FFFu + ((u >> 16) & 1u);      // RNE
    return (unsigned short)(u >> 16);
}
static __device__ __forceinline__ float fb16(unsigned short h) {
    return __uint_as_float(((unsigned)h) << 16);
}

// ---------------- bf16 split trig tables for inv: T[t][k], k=2x -> cos, 2x+1 -> sin
__global__ __launch_bounds__(256) void gen_T_k(unsigned short* __restrict__ Th,
                                               unsigned short* __restrict__ Tl) {
    int lvl = blockIdx.y;
    int nh = 4096 >> lvl;
    int idx = blockIdx.x * 256 + threadIdx.x;
    if (idx >= nh * 128) return;
    int t = idx >> 7, k = idx & 127, x = k >> 1;
    int l = nh / 2 + 1; if (l > 64) l = 64;
    float v = 0.f;
    if (x < l) {
        int r = (x * t) & (nh - 1);
        float th = 6.283185307179586f * ((float)r / (float)nh);
        float s, c; sincosf(th, &s, &c);
        v = (k & 1) ? s : c;
    }
    unsigned short hi = b16(v);
    unsigned short lo = b16(v - fb16(hi));
    size_t off = d_tof(lvl) + idx;
    Th[off] = hi; Tl[off] = lo;
}

// ---------------- decompose: x[b,2t,c,:],x[b,2t+1,c,:] -> d,s via ec_d/ec_s (16x8)
__global__ __launch_bounds__(256) void decomp_k(const float* __restrict__ xin,
        const float* __restrict__ ecd, const float* __restrict__ ecs,
        float* __restrict__ dslot, float* __restrict__ sslot, int nh) {
    int idx = blockIdx.x * 256 + threadIdx.x;
    if (idx >= BB * nh * CC) return;
    int c = idx & 7;
    int t = (idx >> 3) % nh;
    int b = idx / (nh * CC);
    const float* p0 = xin + ((size_t)b * 2 * nh + 2 * t) * CKD + c * KK;
    float xa[16];
    float4 v;
    v = ld4(p0);      xa[0]=v.x; xa[1]=v.y; xa[2]=v.z; xa[3]=v.w;
    v = ld4(p0+4);    xa[4]=v.x; xa[5]=v.y; xa[6]=v.z; xa[7]=v.w;
    v = ld4(p0+64);   xa[8]=v.x; xa[9]=v.y; xa[10]=v.z; xa[11]=v.w;
    v = ld4(p0+68);   xa[12]=v.x; xa[13]=v.y; xa[14]=v.z; xa[15]=v.w;
    float dd[8], ss[8];
    #pragma unroll
    for (int m = 0; m < 8; m++) { dd[m] = 0.f; ss[m] = 0.f; }
    #pragma unroll
    for (int j = 0; j < 16; j++) {
        float xv = xa[j];
        #pragma unroll
        for (int m = 0; m < 8; m++) {
            dd[m] = fmaf(xv, ecd[j*8+m], dd[m]);
            ss[m] = fmaf(xv, ecs[j*8+m], ss[m]);
        }
    }
    size_t ob = ((size_t)b * nh + t) * CKD + c * KK;
    *(float4*)(dslot+ob)   = make_float4(dd[0],dd[1],dd[2],dd[3]);
    *(float4*)(dslot+ob+4) = make_float4(dd[4],dd[5],dd[6],dd[7]);
    *(float4*)(sslot+ob)   = make_float4(ss[0],ss[1],ss[2],ss[3]);
    *(float4*)(sslot+ob+4) = make_float4(ss[4],ss[5],ss[6],ss[7]);
}

// ---------------- forward truncated DFT, ALL levels, computed twiddles (no tables).
__global__ __launch_bounds__(256) void fft_fwd_all_k(const float* __restrict__ outbuf,
        float2* __restrict__ xfp) {
    __shared__ float4 vt4[TT*CKD/4];   // 16 KB  value tile [t][i]
    float* vt = (float*)vt4;
    int slot = blockIdx.x;
    int lvl = 0;
    while (lvl < 12 && slot >= D_CB[lvl+1]) lvl++;
    int nh = 4096 >> lvl;
    int tiles = D_TILES[lvl];
    int ch = D_CB[lvl+1] - D_CB[lvl];
    int tpc = tiles / ch;
    int b = blockIdx.y;
    const float* V = outbuf + (blockIdx.z ? d_uso(lvl) : d_udo(lvl)) + (size_t)b * nh * CKD;
    int tid = threadIdx.x;
    int tx = tid & 15, ty = tid >> 4;
    int tile0 = (slot - D_CB[lvl]) * tpc;
    int tile1 = tile0 + tpc;
    float rn = 6.283185307179586f / (float)nh;
    float2 acc[4][4];
    #pragma unroll
    for (int a = 0; a < 4; a++)
        #pragma unroll
        for (int i = 0; i < 4; i++) acc[a][i] = make_float2(0.f, 0.f);
    for (int tile = tile0; tile < tile1; tile++) {
        int tbase = tile * TT;
        __syncthreads();
        #pragma unroll
        for (int q = 0; q < 4; q++) {
            int fi = tid + 256*q;
            int r = fi >> 4;
            float4 v = make_float4(0.f,0.f,0.f,0.f);
            if (tbase + r < nh) v = ld4(V + (size_t)(tbase + r)*CKD + (fi & 15)*4);
            vt4[fi] = v;
        }
        __syncthreads();
        float2 cs[4], om[4];
        #pragma unroll
        for (int a = 0; a < 4; a++) {
            int xm = ty*4 + a;
            int r0 = (xm * tbase) & (nh - 1);
            __sincosf(rn * (float)r0, &cs[a].y, &cs[a].x);
            int r1 = xm & (nh - 1);
            __sincosf(rn * (float)r1, &om[a].y, &om[a].x);
        }
        #pragma unroll 4
        for (int t = 0; t < TT; t++) {
            float4 vv  = *(float4*)&vt[t*CKD + tx*4];
            float vr[4] = {vv.x, vv.y, vv.z, vv.w};
            #pragma unroll
            for (int a = 0; a < 4; a++) {
                #pragma unroll
                for (int i = 0; i < 4; i++) {
                    acc[a][i].x = fmaf(cs[a].x,  vr[i], acc[a][i].x);
                    acc[a][i].y = fmaf(-cs[a].y, vr[i], acc[a][i].y);
                }
                float nre = cs[a].x*om[a].x - cs[a].y*om[a].y;
                cs[a].y   = cs[a].x*om[a].y + cs[a].y*om[a].x;
                cs[a].x   = nre;
            }
        }
    }
    int x0 = ty*4, i0 = tx*4;
    float2* XFP = xfp + (((size_t)slot*BB + b)*2 + blockIdx.z)*4096;
    #pragma unroll
    for (int a = 0; a < 4; a++)
        #pragma unroll
        for (int i = 0; i < 4; i++)
            XFP[(x0+a)*64 + i0 + i] = acc[a][i];
}

// ---------------- sum per-chunk partials into xf_all[level]
__global__ __launch_bounds__(256) void reduce_all_k(const float2* __restrict__ xfp,
        float2* __restrict__ xf_all) {
    int lvl = blockIdx.y;
    int e = blockIdx.x * 256 + threadIdx.x;      // e < BB*2*4096
    int j = e & 4095;
    int z = (e >> 12) & 1;
    int b = e >> 13;
    int c0 = D_CB[lvl], c1 = D_CB[lvl+1];
    size_t stride = (size_t)BB*2*4096;
    size_t base = (((size_t)c0*BB + b)*2 + z)*4096 + j;
    float2 a = xfp[base];
    for (int c = c0+1; c < c1; c++) {
        base += stride;
        float2 p = xfp[base];
        a.x += p.x; a.y += p.y;
    }
    xf_all[(size_t)lvl*262144 + ((size_t)b*2 + z)*4096 + j] = a;
}

// ---------------- spectral mix, ALL levels: block = (level, mode x)
// writes G = (A, Bn) pre-scaled for irfft, as bf16 hi/lo in [k][o] layout (coalesced)
__global__ __launch_bounds__(256) void mix_all_k(const float2* __restrict__ xf_all,
        const float* __restrict__ wAr, const float* __restrict__ wAi,
        const float* __restrict__ wBr, const float* __restrict__ wBi,
        const float* __restrict__ wCr, const float* __restrict__ wCi,
        unsigned short* __restrict__ ofh, unsigned short* __restrict__ ofl) {
    int lvl = 0;
    while (lvl < 12 && (int)blockIdx.x >= D_LS[lvl+1]) lvl++;
    int x = blockIdx.x - D_LS[lvl];
    int nh = 4096 >> lvl;
    const float2* xfL = xf_all + (size_t)lvl*262144;
    int tid = threadIdx.x;
    int o = tid & 63, wq = tid >> 6;
    __shared__ float2 sxd[BB*CKD];     // 16 KB
    __shared__ float2 sxs[BB*CKD];     // 16 KB
    __shared__ float  swt[6][16*CKD];  // 24 KB
    for (int q = tid; q < BB*CKD; q += 256) {
        int b = q >> 6, i = q & 63;
        sxd[q] = xfL[((size_t)b*2 + 0)*4096 + x*64 + i];
        sxs[q] = xfL[((size_t)b*2 + 1)*4096 + x*64 + i];
    }
    float2 aud[8], aus[8];
    #pragma unroll
    for (int j=0;j<8;j++){ aud[j]=make_float2(0.f,0.f); aus[j]=make_float2(0.f,0.f); }
    for (int ic = 0; ic < 4; ic++) {
        __syncthreads();
        for (int q = tid; q < 16*CKD; q += 256) {
            int ii = q >> 6, oo = q & 63;
            size_t a = ((size_t)(ic*16+ii)*64 + oo)*64 + x;
            swt[0][q] = wAr[a]; swt[1][q] = wAi[a];
            swt[2][q] = wBr[a]; swt[3][q] = wBi[a];
            swt[4][q] = wCr[a]; swt[5][q] = wCi[a];
        }
        __syncthreads();
        #pragma unroll 4
        for (int ii = 0; ii < 16; ii++) {
            float ar = swt[0][ii*64+o], ai_ = swt[1][ii*64+o];
            float br = swt[2][ii*64+o], bi_ = swt[3][ii*64+o];
            float cr = swt[4][ii*64+o], ci_ = swt[5][ii*64+o];
            int i = ic*16 + ii;
            #pragma unroll
            for (int j = 0; j < 8; j++) {
                float2 xd = sxd[(wq*8+j)*64 + i];
                float2 xs = sxs[(wq*8+j)*64 + i];
                aud[j].x += xd.x*ar - xd.y*ai_ + xs.x*br - xs.y*bi_;
                aud[j].y += xd.x*ai_ + xd.y*ar + xs.x*bi_ + xs.y*br;
                aus[j].x += xd.x*cr - xd.y*ci_;
                aus[j].y += xd.x*ci_ + xd.y*cr;
            }
        }
    }
    float w = (x == 0 || 2*x == nh) ? 1.f : 2.f;   // irfft doubling; DC/Nyquist not doubled
    float sc = w / (float)nh;
    int k0 = 2*x;
    #pragma unroll
    for (int j = 0; j < 8; j++) {
        int b = wq*8 + j;
        // z = 0 (ud path)
        {
            size_t base = (((size_t)lvl*32 + b)*2 + 0)*8192;
            float A = sc*aud[j].x, Bn = -sc*aud[j].y;
            unsigned short ha = b16(A),  hb = b16(Bn);
            unsigned short la = b16(A - fb16(ha)), lb = b16(Bn - fb16(hb));
            ofh[base + (size_t)k0*64 + o]     = ha;
            ofh[base + (size_t)(k0+1)*64 + o] = hb;
            ofl[base + (size_t)k0*64 + o]     = la;
            ofl[base + (size_t)(k0+1)*64 + o] = lb;
        }
        // z = 1 (us path)
        {
            size_t base = (((size_t)lvl*32 + b)*2 + 1)*8192;
            float A = sc*aus[j].x, Bn = -sc*aus[j].y;
            unsigned short ha = b16(A),  hb = b16(Bn);
            unsigned short la = b16(A - fb16(ha)), lb = b16(Bn - fb16(hb));
            ofh[base + (size_t)k0*64 + o]     = ha;
            ofh[base + (size_t)(k0+1)*64 + o] = hb;
            ofl[base + (size_t)k0*64 + o]     = la;
            ofl[base + (size_t)(k0+1)*64 + o] = lb;
        }
    }
}

// ---------------- inverse truncated DFT via MFMA (3-term bf16 hi/lo split).
// U[t,o] = sum_k T[t,k] * G[k,o];  grid (133 t-tiles, 32 b, 2 z), 256 thr = 4 waves.
__global__ __launch_bounds__(256) void fft_inv_mfma_k(
        const unsigned short* __restrict__ ofh, const unsigned short* __restrict__ ofl,
        const unsigned short* __restrict__ Th,  const unsigned short* __restrict__ Tl,
        float* __restrict__ outbuf) {
    __shared__ unsigned short gh[64*132];   // [o][k], pitch 132 ush (16.5 KB)
    __shared__ unsigned short gl[64*132];
    int lvl = 0;
    while (lvl < 12 && (int)blockIdx.x >= D_TB[lvl+1]) lvl++;
    int g = blockIdx.x - D_TB[lvl];
    int nh = 4096 >> lvl;
    int tbase = g * 64;
    int b = blockIdx.y, z = blockIdx.z;
    const unsigned short* Gh = ofh + (((size_t)lvl*32 + b)*2 + z)*8192;
    const unsigned short* Gl = ofl + (((size_t)lvl*32 + b)*2 + z)*8192;
    int tid = threadIdx.x;
    // stage G with transpose: [k][o] global -> [o][k] LDS
    #pragma unroll
    for (int q = 0; q < 4; q++) {
        int fi = tid + 256*q;          // 0..1023
        int k = fi & 127, oct = fi >> 7;
        uint4 vh = *(const uint4*)(Gh + (size_t)k*64 + oct*8);
        uint4 vl = *(const uint4*)(Gl + (size_t)k*64 + oct*8);
        const unsigned* ph = &vh.x;
        const unsigned* pl = &vl.x;
        #pragma unroll
        for (int i = 0; i < 8; i++) {
            unsigned wd = ph[i>>1];
            gh[(oct*8+i)*132 + k] = (i&1) ? (unsigned short)(wd>>16) : (unsigned short)(wd&0xFFFF);
            wd = pl[i>>1];
            gl[(oct*8+i)*132 + k] = (i&1) ? (unsigned short)(wd>>16) : (unsigned short)(wd&0xFFFF);
        }
    }
    __syncthreads();
    int w = tid >> 6;
    int lane = tid & 63;
    int tb = tbase + w*16;
    if (tb >= nh) return;
    int trow = lane & 15, khi = lane >> 4;
    int tA = tb + trow; if (tA >= nh) tA = nh - 1;    // clamp (stores guarded)
    const unsigned short* THp = Th + d_tof(lvl) + (size_t)tA*128 + khi*8;
    const unsigned short* TLp = Tl + d_tof(lvl) + (size_t)tA*128 + khi*8;
    f4v acc[4];
    #pragma unroll
    for (int n = 0; n < 4; n++) acc[n] = (f4v){0.f,0.f,0.f,0.f};
    #pragma unroll
    for (int kk = 0; kk < 4; kk++) {
        s8v ah = *(const s8v*)(THp + kk*32);
        s8v al = *(const s8v*)(TLp + kk*32);
        #pragma unroll
        for (int n = 0; n < 4; n++) {
            int off = (n*16 + trow)*132 + kk*32 + khi*8;
            s4v b0 = *(const s4v*)(gh + off);
            s4v b1 = *(const s4v*)(gh + off + 4);
            s4v c0 = *(const s4v*)(gl + off);
            s4v c1 = *(const s4v*)(gl + off + 4);
            s8v bh = __builtin_shufflevector(b0, b1, 0,1,2,3,4,5,6,7);
            s8v bl = __builtin_shufflevector(c0, c1, 0,1,2,3,4,5,6,7);
            acc[n] = __builtin_amdgcn_mfma_f32_16x16x32_bf16(ah, bh, acc[n], 0, 0, 0);
            acc[n] = __builtin_amdgcn_mfma_f32_16x16x32_bf16(ah, bl, acc[n], 0, 0, 0);
            acc[n] = __builtin_amdgcn_mfma_f32_16x16x32_bf16(al, bh, acc[n], 0, 0, 0);
        }
    }
    float* U = outbuf + (z ? d_uso(lvl) : d_udo(lvl)) + (size_t)b * nh * CKD;
    int thi4 = (lane >> 4) * 4;
    #pragma unroll
    for (int n = 0; n < 4; n++) {
        #pragma unroll
        for (int r = 0; r < 4; r++) {
            int t = tb + thi4 + r;
            if (t < nh) U[(size_t)t*64 + n*16 + trow] = acc[n][r];
        }
    }
}

// ---------------- coarsest-level linear: x @ T0_w.T + b
__global__ __launch_bounds__(256) void t0_k(const float* __restrict__ xin,
        const float* __restrict__ w, const float* __restrict__ bias,
        float* __restrict__ xout) {
    int idx = blockIdx.x*256 + threadIdx.x;
    if (idx >= BB*CKD) return;
    int m = idx & 7, c = (idx >> 3) & 7, b = idx >> 6;
    const float* xr = xin + (size_t)b*CKD + c*KK;
    float acc = bias[m];
    #pragma unroll
    for (int j = 0; j < 8; j++) acc = fmaf(xr[j], w[m*8+j], acc);
    xout[idx] = acc;
}

// ---------------- reconstruct one level: (x+Us, Ud) @ rc_e / rc_o, interleave even/odd
__global__ __launch_bounds__(256) void recon_k(const float* __restrict__ xin,
        const float* __restrict__ us, const float* __restrict__ ud,
        const float* __restrict__ rce, const float* __restrict__ rco,
        float* __restrict__ xout, int nh) {
    int idx = blockIdx.x*256 + threadIdx.x;
    if (idx >= BB*nh*CC) return;
    int c = idx & 7;
    int t = (idx >> 3) % nh;
    int b = idx / (nh*CC);
    size_t base = ((size_t)b*nh + t)*CKD + c*KK;
    float xc[16];
    float4 a0 = ld4(xin+base), a1 = ld4(xin+base+4);
    float4 u0 = ld4(us+base),  u1 = ld4(us+base+4);
    float4 d0 = ld4(ud+base),  d1 = ld4(ud+base+4);
    xc[0]=a0.x+u0.x; xc[1]=a0.y+u0.y; xc[2]=a0.z+u0.z; xc[3]=a0.w+u0.w;
    xc[4]=a1.x+u1.x; xc[5]=a1.y+u1.y; xc[6]=a1.z+u1.z; xc[7]=a1.w+u1.w;
    xc[8]=d0.x;  xc[9]=d0.y;  xc[10]=d0.z; xc[11]=d0.w;
    xc[12]=d1.x; xc[13]=d1.y; xc[14]=d1.z; xc[15]=d1.w;
    float e[8], o2[8];
    #pragma unroll
    for (int m = 0; m < 8; m++) { e[m] = 0.f; o2[m] = 0.f; }
    #pragma unroll
    for (int j = 0; j < 16; j++) {
        float xv = xc[j];
        #pragma unroll
        for (int m = 0; m < 8; m++) {
            e[m]  = fmaf(xv, rce[j*8+m], e[m]);
            o2[m] = fmaf(xv, rco[j*8+m], o2[m]);
        }
    }
    size_t ob = ((size_t)b*2*nh + 2*t)*CKD + c*KK;
    *(float4*)(xout+ob)      = make_float4(e[0],e[1],e[2],e[3]);
    *(float4*)(xout+ob+4)    = make_float4(e[4],e[5],e[6],e[7]);
    *(float4*)(xout+ob+64)   = make_float4(o2[0],o2[1],o2[2],o2[3]);
    *(float4*)(xout+ob+68)   = make_float4(o2[4],o2[5],o2[6],o2[7]);
}

extern "C" void kernel_launch(void* const* d_in, const int* in_sizes, int n_in,
                              void* d_out, int out_size, void* d_ws, size_t ws_size,
                              hipStream_t stream) {
    const float* x   = (const float*)d_in[0];
    const float* wAr = (const float*)d_in[1];
    const float* wAi = (const float*)d_in[2];
    const float* wBr = (const float*)d_in[3];
    const float* wBi = (const float*)d_in[4];
    const float* wCr = (const float*)d_in[5];
    const float* wCi = (const float*)d_in[6];
    const float* T0w = (const float*)d_in[7];
    const float* T0b = (const float*)d_in[8];
    const float* ecs = (const float*)d_in[9];
    const float* ecd = (const float*)d_in[10];
    const float* rce = (const float*)d_in[11];
    const float* rco = (const float*)d_in[12];
    float* out = (float*)d_out;
    float* wsf = (float*)d_ws;

    // workspace layout (floats)
    size_t p = 0;
    float2* xf_all = (float2*)(wsf + p); p += 13ull*524288;          // 27 MB
    unsigned short* ofh = (unsigned short*)(wsf + p); p += 3407872;  // 13.6 MB (bf16 hi)
    unsigned short* ofl = (unsigned short*)(wsf + p); p += 3407872;  // 13.6 MB (bf16 lo)
    unsigned short* Th  = (unsigned short*)(wsf + p); p += 528384;   // 2.1 MB
    unsigned short* Tl  = (unsigned short*)(wsf + p); p += 528384;   // 2.1 MB
    float*  xt0  = wsf + p; p += 2048;
    float*  rb0  = wsf + p; p += 4194304;
    float*  rb1  = wsf + p; p += 8388608;
    float2* xfp  = (float2*)(wsf + p); p += 69ull*BB*2*4096*2;       // 145 MB
    (void)ws_size; (void)in_sizes; (void)n_in; (void)out_size;

    size_t udo[13], uso[13];
    for (int i = 0; i < 13; i++) {
        udo[i] = 33554432ull - (16777216u >> i);
        uso[i] = 50329600ull - (16777216u >> i);
    }

    // trig tables for the MFMA inverse (independent of everything else)
    gen_T_k<<<dim3(2048, 13), 256, 0, stream>>>(Th, Tl);

    // sequential decomposition chain (s feeds next level)
    for (int i = 0; i < 13; i++) {
        int nh = 4096 >> i;
        const float* xin_l = (i == 0) ? x : (out + uso[i-1]);
        int tot = BB * nh * CC;
        decomp_k<<<(tot + 255)/256, 256, 0, stream>>>(xin_l, ecd, ecs, out + udo[i], out + uso[i], nh);
    }
    // coarsest-level linear (reads s_12 before inv overwrites it)
    t0_k<<<(BB*CKD + 255)/256, 256, 0, stream>>>(out + uso[12], T0w, T0b, xt0);

    // all-levels spectral pipeline: fwd -> reduce -> mix -> inv(MFMA)
    fft_fwd_all_k<<<dim3(69, BB, 2), 256, 0, stream>>>(out, xfp);
    reduce_all_k<<<dim3(1024, 13), 256, 0, stream>>>(xfp, xf_all);
    mix_all_k<<<454, 256, 0, stream>>>(xf_all, wAr, wAi, wBr, wBi, wCr, wCi, ofh, ofl);
    fft_inv_mfma_k<<<dim3(133, BB, 2), 256, 0, stream>>>(ofh, ofl, Th, Tl, out);

    // sequential reconstruction chain
    const float* rin = xt0;
    for (int i = 12; i >= 0; i--) {
        int nh = 4096 >> i;
        float* ro = (i == 0) ? out : ((i & 1) ? rb1 : rb0);
        int tot = BB * nh * CC;
        recon_k<<<(tot + 255)/256, 256, 0, stream>>>(rin, out + uso[i], out + udo[i], rce, rco, ro, nh);
        rin = ro;
    }
}

// Round 6
// 505.415 us; speedup vs baseline: 1.3351x; 1.1667x over previous
//
#include <hip/hip_runtime.h>

#define BB 32
#define CKD 64
#define CC 8
#define KK 8
#define TT 64
#define FP 136

// level tables (compile-time; N=8192, 13 levels)
__device__ const int D_FCB[14] = {0,8,12,14,15,16,17,18,19,20,21,22,23,24};   // fwd 512-t slot prefix
__device__ const int D_TB[14] = {0,64,96,112,120,124,126,127,128,129,130,131,132,133}; // inv 64-t tile prefix
__device__ const int D_LS[14] = {0,64,128,192,256,320,384,417,434,443,448,451,453,454}; // mix l prefix
__device__ const int D_L[13]  = {64,64,64,64,64,64,33,17,9,5,3,2,1};
__device__ const int D_FTOF[13] = {0,524288,786432,917504,983040,1015808,1032192,
                                   1048576,1064960,1081344,1097728,1114112,1130496}; // fwd table elem offsets

typedef __attribute__((ext_vector_type(4))) short s4v;
typedef __attribute__((ext_vector_type(8))) short s8v;
typedef __attribute__((ext_vector_type(4))) float f4v;

static __device__ __forceinline__ float4 ld4(const float* p){ return *(const float4*)p; }
static __device__ __forceinline__ size_t d_udo(int i){ return 33554432ull - (16777216u >> i); }
static __device__ __forceinline__ size_t d_uso(int i){ return 50329600ull - (16777216u >> i); }
static __device__ __forceinline__ size_t d_tof(int i){ return 128ull * (8192u - (8192u >> i)); }

static __device__ __forceinline__ unsigned short b16(float f) {
    unsigned u = __float_as_uint(f);
    u += 0x7FFFu + ((u >> 16) & 1u);      // RNE
    return (unsigned short)(u >> 16);
}
static __device__ __forceinline__ float fb16(unsigned short h) {
    return __uint_as_float(((unsigned)h) << 16);
}

// ---------------- bf16 split trig tables for inv: T[t][k], k=2x -> cos, 2x+1 -> sin
__global__ __launch_bounds__(256) void gen_T_k(unsigned short* __restrict__ Th,
                                               unsigned short* __restrict__ Tl) {
    int lvl = blockIdx.y;
    int nh = 4096 >> lvl;
    int idx = blockIdx.x * 256 + threadIdx.x;
    if (idx >= nh * 128) return;
    int t = idx >> 7, k = idx & 127, x = k >> 1;
    int l = nh / 2 + 1; if (l > 64) l = 64;
    float v = 0.f;
    if (x < l) {
        int r = (x * t) & (nh - 1);
        float th = 6.283185307179586f * ((float)r / (float)nh);
        float s, c; sincosf(th, &s, &c);
        v = (k & 1) ? s : c;
    }
    unsigned short hi = b16(v);
    unsigned short lo = b16(v - fb16(hi));
    size_t off = d_tof(lvl) + idx;
    Th[off] = hi; Tl[off] = lo;
}

// ---------------- bf16 split trig tables for fwd: F[m][t], m=2x -> cos, 2x+1 -> -sin
// padded to nhp = max(nh,128) columns (zeros beyond nh / beyond mode l)
__global__ __launch_bounds__(256) void gen_Tf_k(unsigned short* __restrict__ Tfh,
                                                unsigned short* __restrict__ Tfl) {
    int lvl = blockIdx.y;
    int nh = 4096 >> lvl;
    int nhp = nh < 128 ? 128 : nh;
    int idx = blockIdx.x * 256 + threadIdx.x;
    if (idx >= 128 * nhp) return;
    int tb = 31 - __clz(nhp);
    int m = idx >> tb, t = idx & (nhp - 1);
    int x = m >> 1;
    int l = nh / 2 + 1; if (l > 64) l = 64;
    float v = 0.f;
    if (x < l && t < nh) {
        int r = (x * t) & (nh - 1);
        float th = 6.283185307179586f * ((float)r / (float)nh);
        float s, c; sincosf(th, &s, &c);
        v = (m & 1) ? -s : c;
    }
    unsigned short hi = b16(v);
    unsigned short lo = b16(v - fb16(hi));
    size_t off = (size_t)D_FTOF[lvl] + idx;
    Tfh[off] = hi; Tfl[off] = lo;
}

// ---------------- decompose: x[b,2t,c,:],x[b,2t+1,c,:] -> d,s via ec_d/ec_s (16x8)
__global__ __launch_bounds__(256) void decomp_k(const float* __restrict__ xin,
        const float* __restrict__ ecd, const float* __restrict__ ecs,
        float* __restrict__ dslot, float* __restrict__ sslot, int nh) {
    int idx = blockIdx.x * 256 + threadIdx.x;
    if (idx >= BB * nh * CC) return;
    int c = idx & 7;
    int t = (idx >> 3) % nh;
    int b = idx / (nh * CC);
    const float* p0 = xin + ((size_t)b * 2 * nh + 2 * t) * CKD + c * KK;
    float xa[16];
    float4 v;
    v = ld4(p0);      xa[0]=v.x; xa[1]=v.y; xa[2]=v.z; xa[3]=v.w;
    v = ld4(p0+4);    xa[4]=v.x; xa[5]=v.y; xa[6]=v.z; xa[7]=v.w;
    v = ld4(p0+64);   xa[8]=v.x; xa[9]=v.y; xa[10]=v.z; xa[11]=v.w;
    v = ld4(p0+68);   xa[12]=v.x; xa[13]=v.y; xa[14]=v.z; xa[15]=v.w;
    float dd[8], ss[8];
    #pragma unroll
    for (int m = 0; m < 8; m++) { dd[m] = 0.f; ss[m] = 0.f; }
    #pragma unroll
    for (int j = 0; j < 16; j++) {
        float xv = xa[j];
        #pragma unroll
        for (int m = 0; m < 8; m++) {
            dd[m] = fmaf(xv, ecd[j*8+m], dd[m]);
            ss[m] = fmaf(xv, ecs[j*8+m], ss[m]);
        }
    }
    size_t ob = ((size_t)b * nh + t) * CKD + c * KK;
    *(float4*)(dslot+ob)   = make_float4(dd[0],dd[1],dd[2],dd[3]);
    *(float4*)(dslot+ob+4) = make_float4(dd[4],dd[5],dd[6],dd[7]);
    *(float4*)(sslot+ob)   = make_float4(ss[0],ss[1],ss[2],ss[3]);
    *(float4*)(sslot+ob+4) = make_float4(ss[4],ss[5],ss[6],ss[7]);
}

// ---------------- forward truncated DFT via MFMA (3-term bf16 hi/lo split).
// XF[m][i] = sum_t F[m][t] * V[t][i]; grid (24 K-slots, 32 b, 2 z), 256 thr = 4 waves.
// wave w: m-tiles {(w&1)*4 .. +3}, n-tiles {(w>>1)*2 .. +1}
__global__ __launch_bounds__(256) void fft_fwd_mfma_k(const float* __restrict__ outbuf,
        const unsigned short* __restrict__ Tfh, const unsigned short* __restrict__ Tfl,
        float* __restrict__ xfpf) {
    __shared__ unsigned short vh[64*FP];   // 17 KB  V bf16-hi [i][t]
    __shared__ unsigned short vl[64*FP];   // 17 KB  V bf16-lo [i][t]
    int slot = blockIdx.x;
    int lvl = 0;
    while (lvl < 12 && slot >= D_FCB[lvl+1]) lvl++;
    int nh = 4096 >> lvl;
    int nhp = nh < 128 ? 128 : nh;
    int t0s = (slot - D_FCB[lvl]) * 512;
    int t1s = t0s + 512; if (t1s > nhp) t1s = nhp;
    int b = blockIdx.y, z = blockIdx.z;
    const float* V = outbuf + (z ? d_uso(lvl) : d_udo(lvl)) + (size_t)b * nh * CKD;
    const unsigned short* TH = Tfh + D_FTOF[lvl];
    const unsigned short* TL = Tfl + D_FTOF[lvl];
    int tid = threadIdx.x;
    int w = tid >> 6, lane = tid & 63;
    int col = lane & 15, khi = lane >> 4;
    int mt0 = (w & 1) * 4, nt0 = (w >> 1) * 2;
    f4v acc[4][2];
    #pragma unroll
    for (int m = 0; m < 4; m++)
        #pragma unroll
        for (int n = 0; n < 2; n++) acc[m][n] = (f4v){0.f,0.f,0.f,0.f};
    for (int tc = t0s; tc < t1s; tc += 128) {
        __syncthreads();
        #pragma unroll
        for (int q = 0; q < 8; q++) {
            int fi = tid + 256*q;            // 2048 float4 = 64i x 128t
            int t = tc + (fi >> 4);
            int i4 = (fi & 15) * 4;
            float4 v = make_float4(0.f,0.f,0.f,0.f);
            if (t < nh) v = ld4(V + (size_t)t*CKD + i4);
            int tl_ = t - tc;
            const float* pv = &v.x;
            #pragma unroll
            for (int j = 0; j < 4; j++) {
                float f = pv[j];
                unsigned short hi = (unsigned short)(__float_as_uint(f) >> 16);
                float r = f - fb16(hi);
                unsigned short lo = (unsigned short)(__float_as_uint(r) >> 16);
                vh[(i4+j)*FP + tl_] = hi;
                vl[(i4+j)*FP + tl_] = lo;
            }
        }
        __syncthreads();
        #pragma unroll
        for (int kk = 0; kk < 4; kk++) {
            int tg = tc + kk*32 + khi*8;
            s8v ah[4], al[4];
            #pragma unroll
            for (int m = 0; m < 4; m++) {
                int row = (mt0 + m)*16 + col;
                ah[m] = *(const s8v*)(TH + (size_t)row*nhp + tg);
                al[m] = *(const s8v*)(TL + (size_t)row*nhp + tg);
            }
            #pragma unroll
            for (int n = 0; n < 2; n++) {
                int off = ((nt0 + n)*16 + col)*FP + kk*32 + khi*8;
                s8v bh = *(const s8v*)(vh + off);
                s8v bl = *(const s8v*)(vl + off);
                #pragma unroll
                for (int m = 0; m < 4; m++) {
                    acc[m][n] = __builtin_amdgcn_mfma_f32_16x16x32_bf16(ah[m], bh, acc[m][n], 0,0,0);
                    acc[m][n] = __builtin_amdgcn_mfma_f32_16x16x32_bf16(ah[m], bl, acc[m][n], 0,0,0);
                    acc[m][n] = __builtin_amdgcn_mfma_f32_16x16x32_bf16(al[m], bh, acc[m][n], 0,0,0);
                }
            }
        }
    }
    float* P = xfpf + ((size_t)slot*64 + (size_t)b*2 + z) * 8192;
    #pragma unroll
    for (int m = 0; m < 4; m++) {
        int m0 = (mt0 + m)*16 + khi*4;
        #pragma unroll
        for (int n = 0; n < 2; n++) {
            int ic = (nt0 + n)*16 + col;
            #pragma unroll
            for (int r = 0; r < 4; r++)
                P[(size_t)(m0 + r)*64 + ic] = acc[m][n][r];
        }
    }
}

// ---------------- sum fwd partials, relayout [m][i] fp32 -> [x][i] float2 in xf_all
__global__ __launch_bounds__(256) void reduce_fwd_k(const float* __restrict__ xfpf,
        float2* __restrict__ xf_all) {
    int lvl = blockIdx.y;
    int e = blockIdx.x * 256 + threadIdx.x;   // < 64*4096
    int j = e & 4095;
    int bz = e >> 12;
    int x = j >> 6, i = j & 63;
    int c0 = D_FCB[lvl], c1 = D_FCB[lvl+1];
    float re = 0.f, im = 0.f;
    for (int c = c0; c < c1; c++) {
        size_t base = ((size_t)c*64 + bz) * 8192;
        re += xfpf[base + (size_t)(2*x)*64 + i];
        im += xfpf[base + (size_t)(2*x+1)*64 + i];
    }
    xf_all[(size_t)lvl*262144 + (size_t)bz*4096 + j] = make_float2(re, im);
}

// ---------------- spectral mix, ALL levels: block = (level, mode x)
// writes G = (A, Bn) pre-scaled for irfft, as bf16 hi/lo in [k][o] layout (coalesced)
__global__ __launch_bounds__(256) void mix_all_k(const float2* __restrict__ xf_all,
        const float* __restrict__ wAr, const float* __restrict__ wAi,
        const float* __restrict__ wBr, const float* __restrict__ wBi,
        const float* __restrict__ wCr, const float* __restrict__ wCi,
        unsigned short* __restrict__ ofh, unsigned short* __restrict__ ofl) {
    int lvl = 0;
    while (lvl < 12 && (int)blockIdx.x >= D_LS[lvl+1]) lvl++;
    int x = blockIdx.x - D_LS[lvl];
    int nh = 4096 >> lvl;
    const float2* xfL = xf_all + (size_t)lvl*262144;
    int tid = threadIdx.x;
    int o = tid & 63, wq = tid >> 6;
    __shared__ float2 sxd[BB*CKD];     // 16 KB
    __shared__ float2 sxs[BB*CKD];     // 16 KB
    __shared__ float  swt[6][16*CKD];  // 24 KB
    for (int q = tid; q < BB*CKD; q += 256) {
        int b = q >> 6, i = q & 63;
        sxd[q] = xfL[((size_t)b*2 + 0)*4096 + x*64 + i];
        sxs[q] = xfL[((size_t)b*2 + 1)*4096 + x*64 + i];
    }
    float2 aud[8], aus[8];
    #pragma unroll
    for (int j=0;j<8;j++){ aud[j]=make_float2(0.f,0.f); aus[j]=make_float2(0.f,0.f); }
    for (int ic = 0; ic < 4; ic++) {
        __syncthreads();
        for (int q = tid; q < 16*CKD; q += 256) {
            int ii = q >> 6, oo = q & 63;
            size_t a = ((size_t)(ic*16+ii)*64 + oo)*64 + x;
            swt[0][q] = wAr[a]; swt[1][q] = wAi[a];
            swt[2][q] = wBr[a]; swt[3][q] = wBi[a];
            swt[4][q] = wCr[a]; swt[5][q] = wCi[a];
        }
        __syncthreads();
        #pragma unroll 4
        for (int ii = 0; ii < 16; ii++) {
            float ar = swt[0][ii*64+o], ai_ = swt[1][ii*64+o];
            float br = swt[2][ii*64+o], bi_ = swt[3][ii*64+o];
            float cr = swt[4][ii*64+o], ci_ = swt[5][ii*64+o];
            int i = ic*16 + ii;
            #pragma unroll
            for (int j = 0; j < 8; j++) {
                float2 xd = sxd[(wq*8+j)*64 + i];
                float2 xs = sxs[(wq*8+j)*64 + i];
                aud[j].x += xd.x*ar - xd.y*ai_ + xs.x*br - xs.y*bi_;
                aud[j].y += xd.x*ai_ + xd.y*ar + xs.x*bi_ + xs.y*br;
                aus[j].x += xd.x*cr - xd.y*ci_;
                aus[j].y += xd.x*ci_ + xd.y*cr;
            }
        }
    }
    float w = (x == 0 || 2*x == nh) ? 1.f : 2.f;   // irfft doubling; DC/Nyquist not doubled
    float sc = w / (float)nh;
    int k0 = 2*x;
    #pragma unroll
    for (int j = 0; j < 8; j++) {
        int b = wq*8 + j;
        {
            size_t base = (((size_t)lvl*32 + b)*2 + 0)*8192;
            float A = sc*aud[j].x, Bn = -sc*aud[j].y;
            unsigned short ha = b16(A),  hb = b16(Bn);
            unsigned short la = b16(A - fb16(ha)), lb = b16(Bn - fb16(hb));
            ofh[base + (size_t)k0*64 + o]     = ha;
            ofh[base + (size_t)(k0+1)*64 + o] = hb;
            ofl[base + (size_t)k0*64 + o]     = la;
            ofl[base + (size_t)(k0+1)*64 + o] = lb;
        }
        {
            size_t base = (((size_t)lvl*32 + b)*2 + 1)*8192;
            float A = sc*aus[j].x, Bn = -sc*aus[j].y;
            unsigned short ha = b16(A),  hb = b16(Bn);
            unsigned short la = b16(A - fb16(ha)), lb = b16(Bn - fb16(hb));
            ofh[base + (size_t)k0*64 + o]     = ha;
            ofh[base + (size_t)(k0+1)*64 + o] = hb;
            ofl[base + (size_t)k0*64 + o]     = la;
            ofl[base + (size_t)(k0+1)*64 + o] = lb;
        }
    }
}

// ---------------- inverse truncated DFT via MFMA (3-term bf16 hi/lo split).
// U[t,o] = sum_k T[t,k] * G[k,o];  grid (133 t-tiles, 32 b, 2 z), 256 thr = 4 waves.
__global__ __launch_bounds__(256) void fft_inv_mfma_k(
        const unsigned short* __restrict__ ofh, const unsigned short* __restrict__ ofl,
        const unsigned short* __restrict__ Th,  const unsigned short* __restrict__ Tl,
        float* __restrict__ outbuf) {
    __shared__ unsigned short gh[64*132];   // [o][k], pitch 132 ush (16.5 KB)
    __shared__ unsigned short gl[64*132];
    int lvl = 0;
    while (lvl < 12 && (int)blockIdx.x >= D_TB[lvl+1]) lvl++;
    int g = blockIdx.x - D_TB[lvl];
    int nh = 4096 >> lvl;
    int tbase = g * 64;
    int b = blockIdx.y, z = blockIdx.z;
    const unsigned short* Gh = ofh + (((size_t)lvl*32 + b)*2 + z)*8192;
    const unsigned short* Gl = ofl + (((size_t)lvl*32 + b)*2 + z)*8192;
    int tid = threadIdx.x;
    #pragma unroll
    for (int q = 0; q < 4; q++) {
        int fi = tid + 256*q;          // 0..1023
        int k = fi & 127, oct = fi >> 7;
        uint4 vh = *(const uint4*)(Gh + (size_t)k*64 + oct*8);
        uint4 vl = *(const uint4*)(Gl + (size_t)k*64 + oct*8);
        const unsigned* ph = &vh.x;
        const unsigned* pl = &vl.x;
        #pragma unroll
        for (int i = 0; i < 8; i++) {
            unsigned wd = ph[i>>1];
            gh[(oct*8+i)*132 + k] = (i&1) ? (unsigned short)(wd>>16) : (unsigned short)(wd&0xFFFF);
            wd = pl[i>>1];
            gl[(oct*8+i)*132 + k] = (i&1) ? (unsigned short)(wd>>16) : (unsigned short)(wd&0xFFFF);
        }
    }
    __syncthreads();
    int w = tid >> 6;
    int lane = tid & 63;
    int tb = tbase + w*16;
    if (tb >= nh) return;
    int trow = lane & 15, khi = lane >> 4;
    int tA = tb + trow; if (tA >= nh) tA = nh - 1;    // clamp (stores guarded)
    const unsigned short* THp = Th + d_tof(lvl) + (size_t)tA*128 + khi*8;
    const unsigned short* TLp = Tl + d_tof(lvl) + (size_t)tA*128 + khi*8;
    f4v acc[4];
    #pragma unroll
    for (int n = 0; n < 4; n++) acc[n] = (f4v){0.f,0.f,0.f,0.f};
    #pragma unroll
    for (int kk = 0; kk < 4; kk++) {
        s8v ah = *(const s8v*)(THp + kk*32);
        s8v al = *(const s8v*)(TLp + kk*32);
        #pragma unroll
        for (int n = 0; n < 4; n++) {
            int off = (n*16 + trow)*132 + kk*32 + khi*8;
            s4v b0 = *(const s4v*)(gh + off);
            s4v b1 = *(const s4v*)(gh + off + 4);
            s4v c0 = *(const s4v*)(gl + off);
            s4v c1 = *(const s4v*)(gl + off + 4);
            s8v bh = __builtin_shufflevector(b0, b1, 0,1,2,3,4,5,6,7);
            s8v bl = __builtin_shufflevector(c0, c1, 0,1,2,3,4,5,6,7);
            acc[n] = __builtin_amdgcn_mfma_f32_16x16x32_bf16(ah, bh, acc[n], 0, 0, 0);
            acc[n] = __builtin_amdgcn_mfma_f32_16x16x32_bf16(ah, bl, acc[n], 0, 0, 0);
            acc[n] = __builtin_amdgcn_mfma_f32_16x16x32_bf16(al, bh, acc[n], 0, 0, 0);
        }
    }
    float* U = outbuf + (z ? d_uso(lvl) : d_udo(lvl)) + (size_t)b * nh * CKD;
    int thi4 = (lane >> 4) * 4;
    #pragma unroll
    for (int n = 0; n < 4; n++) {
        #pragma unroll
        for (int r = 0; r < 4; r++) {
            int t = tb + thi4 + r;
            if (t < nh) U[(size_t)t*64 + n*16 + trow] = acc[n][r];
        }
    }
}

// ---------------- coarsest-level linear: x @ T0_w.T + b
__global__ __launch_bounds__(256) void t0_k(const float* __restrict__ xin,
        const float* __restrict__ w, const float* __restrict__ bias,
        float* __restrict__ xout) {
    int idx = blockIdx.x*256 + threadIdx.x;
    if (idx >= BB*CKD) return;
    int m = idx & 7, c = (idx >> 3) & 7, b = idx >> 6;
    const float* xr = xin + (size_t)b*CKD + c*KK;
    float acc = bias[m];
    #pragma unroll
    for (int j = 0; j < 8; j++) acc = fmaf(xr[j], w[m*8+j], acc);
    xout[idx] = acc;
}

// ---------------- reconstruct one level: (x+Us, Ud) @ rc_e / rc_o, interleave even/odd
__global__ __launch_bounds__(256) void recon_k(const float* __restrict__ xin,
        const float* __restrict__ us, const float* __restrict__ ud,
        const float* __restrict__ rce, const float* __restrict__ rco,
        float* __restrict__ xout, int nh) {
    int idx = blockIdx.x*256 + threadIdx.x;
    if (idx >= BB*nh*CC) return;
    int c = idx & 7;
    int t = (idx >> 3) % nh;
    int b = idx / (nh*CC);
    size_t base = ((size_t)b*nh + t)*CKD + c*KK;
    float xc[16];
    float4 a0 = ld4(xin+base), a1 = ld4(xin+base+4);
    float4 u0 = ld4(us+base),  u1 = ld4(us+base+4);
    float4 d0 = ld4(ud+base),  d1 = ld4(ud+base+4);
    xc[0]=a0.x+u0.x; xc[1]=a0.y+u0.y; xc[2]=a0.z+u0.z; xc[3]=a0.w+u0.w;
    xc[4]=a1.x+u1.x; xc[5]=a1.y+u1.y; xc[6]=a1.z+u1.z; xc[7]=a1.w+u1.w;
    xc[8]=d0.x;  xc[9]=d0.y;  xc[10]=d0.z; xc[11]=d0.w;
    xc[12]=d1.x; xc[13]=d1.y; xc[14]=d1.z; xc[15]=d1.w;
    float e[8], o2[8];
    #pragma unroll
    for (int m = 0; m < 8; m++) { e[m] = 0.f; o2[m] = 0.f; }
    #pragma unroll
    for (int j = 0; j < 16; j++) {
        float xv = xc[j];
        #pragma unroll
        for (int m = 0; m < 8; m++) {
            e[m]  = fmaf(xv, rce[j*8+m], e[m]);
            o2[m] = fmaf(xv, rco[j*8+m], o2[m]);
        }
    }
    size_t ob = ((size_t)b*2*nh + 2*t)*CKD + c*KK;
    *(float4*)(xout+ob)      = make_float4(e[0],e[1],e[2],e[3]);
    *(float4*)(xout+ob+4)    = make_float4(e[4],e[5],e[6],e[7]);
    *(float4*)(xout+ob+64)   = make_float4(o2[0],o2[1],o2[2],o2[3]);
    *(float4*)(xout+ob+68)   = make_float4(o2[4],o2[5],o2[6],o2[7]);
}

extern "C" void kernel_launch(void* const* d_in, const int* in_sizes, int n_in,
                              void* d_out, int out_size, void* d_ws, size_t ws_size,
                              hipStream_t stream) {
    const float* x   = (const float*)d_in[0];
    const float* wAr = (const float*)d_in[1];
    const float* wAi = (const float*)d_in[2];
    const float* wBr = (const float*)d_in[3];
    const float* wBi = (const float*)d_in[4];
    const float* wCr = (const float*)d_in[5];
    const float* wCi = (const float*)d_in[6];
    const float* T0w = (const float*)d_in[7];
    const float* T0b = (const float*)d_in[8];
    const float* ecs = (const float*)d_in[9];
    const float* ecd = (const float*)d_in[10];
    const float* rce = (const float*)d_in[11];
    const float* rco = (const float*)d_in[12];
    float* out = (float*)d_out;
    float* wsf = (float*)d_ws;

    // workspace layout (floats)
    size_t p = 0;
    float2* xf_all = (float2*)(wsf + p); p += 6815744;               // 27 MB
    unsigned short* ofh = (unsigned short*)(wsf + p); p += 3407872;  // 13.6 MB (bf16 hi)
    unsigned short* ofl = (unsigned short*)(wsf + p); p += 3407872;  // 13.6 MB (bf16 lo)
    unsigned short* Th  = (unsigned short*)(wsf + p); p += 528384;   // 2.1 MB (inv trig hi)
    unsigned short* Tl  = (unsigned short*)(wsf + p); p += 528384;   // 2.1 MB
    unsigned short* Tfh = (unsigned short*)(wsf + p); p += 573440;   // 2.3 MB (fwd trig hi)
    unsigned short* Tfl = (unsigned short*)(wsf + p); p += 573440;   // 2.3 MB
    float*  xt0  = wsf + p; p += 2048;
    float*  rb0  = wsf + p; p += 4194304;
    float*  rb1  = wsf + p; p += 8388608;
    float*  xfpf = wsf + p; p += 12582912;                           // 50 MB fwd partials
    (void)ws_size; (void)in_sizes; (void)n_in; (void)out_size;

    size_t udo[13], uso[13];
    for (int i = 0; i < 13; i++) {
        udo[i] = 33554432ull - (16777216u >> i);
        uso[i] = 50329600ull - (16777216u >> i);
    }

    // trig tables (independent of data chain)
    gen_T_k<<<dim3(2048, 13), 256, 0, stream>>>(Th, Tl);
    gen_Tf_k<<<dim3(2048, 13), 256, 0, stream>>>(Tfh, Tfl);

    // sequential decomposition chain (s feeds next level)
    for (int i = 0; i < 13; i++) {
        int nh = 4096 >> i;
        const float* xin_l = (i == 0) ? x : (out + uso[i-1]);
        int tot = BB * nh * CC;
        decomp_k<<<(tot + 255)/256, 256, 0, stream>>>(xin_l, ecd, ecs, out + udo[i], out + uso[i], nh);
    }
    // coarsest-level linear (reads s_12 before inv overwrites it)
    t0_k<<<(BB*CKD + 255)/256, 256, 0, stream>>>(out + uso[12], T0w, T0b, xt0);

    // all-levels spectral pipeline: fwd(MFMA) -> reduce -> mix -> inv(MFMA)
    fft_fwd_mfma_k<<<dim3(24, BB, 2), 256, 0, stream>>>(out, Tfh, Tfl, xfpf);
    reduce_fwd_k<<<dim3(1024, 13), 256, 0, stream>>>(xfpf, xf_all);
    mix_all_k<<<454, 256, 0, stream>>>(xf_all, wAr, wAi, wBr, wBi, wCr, wCi, ofh, ofl);
    fft_inv_mfma_k<<<dim3(133, BB, 2), 256, 0, stream>>>(ofh, ofl, Th, Tl, out);

    // sequential reconstruction chain
    const float* rin = xt0;
    for (int i = 12; i >= 0; i--) {
        int nh = 4096 >> i;
        float* ro = (i == 0) ? out : ((i & 1) ? rb1 : rb0);
        int tot = BB * nh * CC;
        recon_k<<<(tot + 255)/256, 256, 0, stream>>>(rin, out + uso[i], out + udo[i], rce, rco, ro, nh);
        rin = ro;
    }
}